// Round 2
// baseline (236.414 us; speedup 1.0000x reference)
//
#include <hip/hip_runtime.h>
#include <hip/hip_bf16.h>

// CoarseGraining: y[i,b] = heg[b] * sum_j exp(-beta[j,b] * d2(i,j)) * wrho[j]
// N = M = 8192, NB = 16, WIDTH = 32. Inputs float32, output float32.
// R10 wave-per-i: 183us. R11 2 i's/wave: 155us. R12 j-split x2: 181us REGRESSION.
// R13 float2-packed math: 133us (VALUBusy 79%, HBM 0.3%, occ 31% grid-capped).
// R14 FAILED (absmax 1.02): magic-number range reduction n=(p+MAG)-MAG was
//   algebraically folded (value-unsafe FP opt) -> r=0 -> result 2^round(p).
// R15: same experiment, fold-immune exp2 poly: n = rintf(p) (v_rndne_f32,
//   opaque), r = p-n exact, scale from INTEGER side bit_cast((max(ni,-127)
//   +127)<<23). Same op count (~9/pair), all full-rate. Keep depth-1 prefetch.
// Prediction: pass at absmax ~2e-4; ~95-110us if trans pipe co-issues with
// main VALU across waves, flat ~130-140us if trans blocks the issue port.

#define N_PTS 8192
#define M_PTS 8192
#define NBASIS 16
#define WIDTH 32

typedef float v2f __attribute__((ext_vector_type(2)));

__device__ __forceinline__ float exp2_hw(float x) { return __builtin_amdgcn_exp2f(x); }
__device__ __forceinline__ float log2_hw(float x) { return __builtin_amdgcn_logf(x); }

__device__ __forceinline__ float fast_tanh(float z) {
    float a = fabsf(z);
    float t = __expf(-2.0f * a);
    float r = (1.0f - t) / (1.0f + t);
    return copysignf(r, z);
}

__device__ __forceinline__ float log_cosh_f(float x) {
    float a = fabsf(x);
    return a + __logf(1.0f + __expf(-2.0f * a)) - 0.6931471805599453f;
}

// Packed exp2 for a pair (i0,i1): full-rate ops only, no trans pipe.
// Rounding via v_rndne_f32 (rintf) -- NOT the (p+MAG)-MAG magic trick, which
// value-unsafe FP optimization folds to n=p (R14 failure). Scale 2^n built on
// the integer side: s = bit_cast((max(ni,-127)+127)<<23); clamp gives exact
// 0.0f for n <= -127 (true value subnormal ~0). Valid for p <= 0 (always:
// p = -log2e*beta*d2, beta >= 0, d2 >= 0).
__device__ __forceinline__ v2f exp2_pair_poly(v2f p) {
    v2f n = { rintf(p.x), rintf(p.y) };        // v_rndne_f32, opaque to FP rewrites
    v2f r = p - n;                             // exact, r in [-0.5, 0.5]
    int nx = (int)n.x;                         // exact: n is integer-valued
    int ny = (int)n.y;
    nx = nx < -127 ? -127 : nx;
    ny = ny < -127 ? -127 : ny;
    v2f s = { __builtin_bit_cast(float, (nx + 127) << 23),
              __builtin_bit_cast(float, (ny + 127) << 23) };
    // cephes exp2f: 1 + r*P(r), deg-5 P, max rel err ~2e-8
    v2f q = r * 1.535336188319500e-4f + 1.339887440266574e-3f;
    q = q * r + 9.618437357674640e-3f;
    q = q * r + 5.550332471162809e-2f;
    q = q * r + 2.402264791363012e-1f;
    q = q * r + 6.931472028550421e-1f;
    q = q * r + 1.0f;
    return q * s;
}

// ---------------- Stage 1: per-source-point quantities ----------------
// cw[j]        = (cx, cy, cz, wrho)
// bnq[q*N + j] = float4{ bn[j][4q..4q+3] }, bn = -log2(e)*beta (q-plane layout)
// hegf[0..15]  = log_cosh(embed(0))^1.5
__global__ __launch_bounds__(64)
void cg_prep(const float* __restrict__ rho,
             const float* __restrict__ gamma,
             const float* __restrict__ coords,
             const float* __restrict__ weights,
             const float* __restrict__ w1,
             const float* __restrict__ b1,
             const float* __restrict__ w2,
             const float* __restrict__ b2,
             float4* __restrict__ cw,
             float4* __restrict__ bnq,
             float* __restrict__ hegf)
{
    const float PI_F = 3.14159265358979323846f;
    const float LOG2E = 1.4426950408889634f;

    __shared__ float s_w1[WIDTH], s_b1[WIDTH], s_w2[WIDTH * NBASIS], s_b2[NBASIS];
    int t = threadIdx.x;
    if (t < WIDTH) { s_w1[t] = w1[t]; s_b1[t] = b1[t]; }
    if (t < NBASIS) s_b2[t] = b2[t];
    #pragma unroll
    for (int k = 0; k < 8; ++k) s_w2[t + 64 * k] = w2[t + 64 * k];
    __syncthreads();

    int j = blockIdx.x * 64 + t;
    {
        float r = rho[j];
        float g = gamma[j];
        const float c83 = 38.28312007948569f;              // 4*(3*pi^2)^(2/3)
        float r83 = exp2_hw(2.6666666667f * log2_hw(r));   // r^(8/3)
        float s2 = g / (c83 * r83);
        float x = __logf(s2 + 1e-4f);

        float emb[NBASIS];
        #pragma unroll
        for (int b = 0; b < NBASIS; ++b) emb[b] = s_b2[b];
        #pragma unroll 4
        for (int w = 0; w < WIDTH; ++w) {
            float h = fast_tanh(fmaf(x, s_w1[w], s_b1[w]));
            #pragma unroll
            for (int b = 0; b < NBASIS; ++b)
                emb[b] = fmaf(h, s_w2[w * NBASIS + b], emb[b]);
        }
        float pref = PI_F * exp2_hw(0.6666666667f * log2_hw(0.5f * r));
        float scale = -LOG2E * pref;
        #pragma unroll
        for (int q = 0; q < 4; ++q) {
            bnq[q * N_PTS + j] = make_float4(scale * log_cosh_f(emb[4 * q + 0]),
                                             scale * log_cosh_f(emb[4 * q + 1]),
                                             scale * log_cosh_f(emb[4 * q + 2]),
                                             scale * log_cosh_f(emb[4 * q + 3]));
        }

        cw[j] = make_float4(coords[j * 3 + 0],
                            coords[j * 3 + 1],
                            coords[j * 3 + 2],
                            weights[j] * r);
    }

    if (blockIdx.x == 0 && t == 0) {
        float emb0[NBASIS];
        #pragma unroll
        for (int b = 0; b < NBASIS; ++b) emb0[b] = s_b2[b];
        for (int w = 0; w < WIDTH; ++w) {
            float h = fast_tanh(s_b1[w]);   // x = 0
            #pragma unroll
            for (int b = 0; b < NBASIS; ++b)
                emb0[b] = fmaf(h, s_w2[w * NBASIS + b], emb0[b]);
        }
        #pragma unroll
        for (int b = 0; b < NBASIS; ++b) {
            float lc = fmaxf(log_cosh_f(emb0[b]), 0.0f);
            hegf[b] = lc * sqrtf(lc);       // lc^1.5
        }
    }
}

// ---------------- Stage 2: all-pairs, 2 i's/wave, hybrid exp ----------
// wave w owns i0=2w, i1=2w+1; lane L handles j = 64k+L.
// Basis planes q=0..2: v_exp_f32 (trans pipe). Plane q=3: packed poly (main
// pipe). Depth-1 register prefetch of next j-tile. 1024 blocks x 4 waves.
__global__ __launch_bounds__(256, 4)
void cg_pairs(const float* __restrict__ oc,
              const float4* __restrict__ cw,
              const float4* __restrict__ bnq,
              const float* __restrict__ hegf,
              float* __restrict__ out)
{
    int wave = (blockIdx.x << 2) | (threadIdx.x >> 6);
    int lane = threadIdx.x & 63;
    int i0 = wave << 1;
    int i1 = i0 | 1;

    v2f oxv = { oc[i0 * 3 + 0], oc[i1 * 3 + 0] };
    v2f oyv = { oc[i0 * 3 + 1], oc[i1 * 3 + 1] };
    v2f ozv = { oc[i0 * 3 + 2], oc[i1 * 3 + 2] };

    v2f acc[NBASIS];
    #pragma unroll
    for (int b = 0; b < NBASIS; ++b) acc[b] = (v2f)0.0f;

    // hw-exp plane: 8 v_exp_f32 on the trans pipe
    auto hwq = [&](const float4& B, v2f d2, v2f w, int o) {
        v2f p0 = B.x * d2;
        v2f p1 = B.y * d2;
        v2f p2 = B.z * d2;
        v2f p3 = B.w * d2;
        v2f e0 = { exp2_hw(p0.x), exp2_hw(p0.y) };
        v2f e1 = { exp2_hw(p1.x), exp2_hw(p1.y) };
        v2f e2 = { exp2_hw(p2.x), exp2_hw(p2.y) };
        v2f e3 = { exp2_hw(p3.x), exp2_hw(p3.y) };
        acc[o + 0] += e0 * w;
        acc[o + 1] += e1 * w;
        acc[o + 2] += e2 * w;
        acc[o + 3] += e3 * w;
    };
    // poly plane: all full-rate packed ops on the main pipe
    auto polyq = [&](const float4& B, v2f d2, v2f w, int o) {
        v2f p0 = B.x * d2;
        v2f p1 = B.y * d2;
        v2f p2 = B.z * d2;
        v2f p3 = B.w * d2;
        acc[o + 0] += exp2_pair_poly(p0) * w;
        acc[o + 1] += exp2_pair_poly(p1) * w;
        acc[o + 2] += exp2_pair_poly(p2) * w;
        acc[o + 3] += exp2_pair_poly(p3) * w;
    };
    auto body = [&](const float4& c, const float4& B0, const float4& B1,
                    const float4& B2, const float4& B3) {
        v2f dx = oxv - c.x;
        v2f dy = oyv - c.y;
        v2f dz = ozv - c.z;
        v2f d2 = dx * dx + dy * dy + dz * dz;
        v2f w = (v2f)c.w;
        hwq(B0, d2, w, 0);
        hwq(B1, d2, w, 4);
        hwq(B2, d2, w, 8);
        polyq(B3, d2, w, 12);
    };

    // prologue loads (j-tile 0)
    float4 c_c  = cw[lane];
    float4 b0_c = bnq[0 * N_PTS + lane];
    float4 b1_c = bnq[1 * N_PTS + lane];
    float4 b2_c = bnq[2 * N_PTS + lane];
    float4 b3_c = bnq[3 * N_PTS + lane];

    for (int k = 0; k < N_PTS / 64 - 1; ++k) {
        int jn = ((k + 1) << 6) | lane;          // coalesced, next tile
        float4 c_n  = cw[jn];
        float4 b0_n = bnq[0 * N_PTS + jn];
        float4 b1_n = bnq[1 * N_PTS + jn];
        float4 b2_n = bnq[2 * N_PTS + jn];
        float4 b3_n = bnq[3 * N_PTS + jn];

        body(c_c, b0_c, b1_c, b2_c, b3_c);

        c_c = c_n; b0_c = b0_n; b1_c = b1_n; b2_c = b2_n; b3_c = b3_n;
    }
    body(c_c, b0_c, b1_c, b2_c, b3_c);           // epilogue tile k = 127

    // 6-step butterfly over 64 lanes, 16 v2f values
    #pragma unroll
    for (int m = 1; m < 64; m <<= 1) {
        #pragma unroll
        for (int b = 0; b < NBASIS; ++b) {
            v2f other = { __shfl_xor(acc[b].x, m, 64),
                          __shfl_xor(acc[b].y, m, 64) };
            acc[b] += other;
        }
    }

    if (lane == 0) {
        float4* o0 = (float4*)(out + i0 * NBASIS);
        float4* o1 = (float4*)(out + i1 * NBASIS);
        #pragma unroll
        for (int q = 0; q < 4; ++q) {
            float h0 = hegf[4 * q + 0];
            float h1 = hegf[4 * q + 1];
            float h2 = hegf[4 * q + 2];
            float h3 = hegf[4 * q + 3];
            o0[q] = make_float4(acc[4 * q + 0].x * h0, acc[4 * q + 1].x * h1,
                                acc[4 * q + 2].x * h2, acc[4 * q + 3].x * h3);
            o1[q] = make_float4(acc[4 * q + 0].y * h0, acc[4 * q + 1].y * h1,
                                acc[4 * q + 2].y * h2, acc[4 * q + 3].y * h3);
        }
    }
}

extern "C" void kernel_launch(void* const* d_in, const int* in_sizes, int n_in,
                              void* d_out, int out_size, void* d_ws, size_t ws_size,
                              hipStream_t stream) {
    const float* rho        = (const float*)d_in[0];
    const float* gamma      = (const float*)d_in[1];
    const float* coords     = (const float*)d_in[2];
    const float* weights    = (const float*)d_in[3];
    const float* out_coords = (const float*)d_in[4];
    const float* w1         = (const float*)d_in[5];
    const float* b1         = (const float*)d_in[6];
    const float* w2         = (const float*)d_in[7];
    const float* b2         = (const float*)d_in[8];

    char* ws = (char*)d_ws;
    // ws layout (640 KiB + 64 B):
    //   cw   : N * float4              = 128 KiB  @ 0
    //   bnq  : 4 planes * N * float4   = 512 KiB  @ 128K
    //   hegf : 16 * float                          @ 640K
    float4* cw   = (float4*)(ws);
    float4* bnq  = (float4*)(ws + (128 << 10));
    float*  hegf = (float*) (ws + (640 << 10));

    cg_prep<<<N_PTS / 64, 64, 0, stream>>>(rho, gamma, coords, weights,
                                           w1, b1, w2, b2,
                                           cw, bnq, hegf);

    cg_pairs<<<M_PTS / 8, 256, 0, stream>>>(out_coords, cw, bnq, hegf,
                                            (float*)d_out);
}